// Round 5
// baseline (371.947 us; speedup 1.0000x reference)
//
#include <hip/hip_runtime.h>
#include <hip/hip_cooperative_groups.h>
#include <math.h>

namespace cg = cooperative_groups;

// Problem dims (fixed by reference)
#define BATCH 32
#define CH    1024     // C == P
#define NPix  784      // H*W = 28*28
#define MMOD  4        // M models, Q == 1
#define JCH   8        // channel-chunks per batch
#define CPB   128      // channels per block (CH/JCH)
#define TB    832      // 13 waves

__device__ __forceinline__ float wave_reduce(float s) {
    #pragma unroll
    for (int off = 32; off; off >>= 1) s += __shfl_down(s, off, 64);
    return s;
}

// One cooperative kernel, 256 blocks x 832 threads (1 block/CU, co-resident).
// Block (b,j) owns channels [j*128,(j+1)*128) of batch b across all phases:
//   P1 norms (inv stays in LDS) -> P2 z-partials (x re-read is L2-warm) ->
//   gsync -> P3 h[b] (j==0 blocks) -> gsync -> P4 out row-dots (x L2/L3-warm).
// R4 lesson: fixed harness floor ~120us; this attacks the ~65us kernel part
// (3 launch gaps, inv roundtrip, 4x smaller zpart, cross-phase L2 locality).
__global__ __launch_bounds__(TB) void k_fused(const float* __restrict__ x,
                                              const float* __restrict__ Wm,
                                              float* __restrict__ zpart,  // [B][J][M][N]
                                              float* __restrict__ h,      // [B][N]
                                              float* __restrict__ out) {
    __shared__ float inv_l[CPB];
    __shared__ float wl[MMOD][CPB];
    __shared__ float h_l[NPix];
    __shared__ float red[13][MMOD];
    __shared__ float s2s[MMOD];

    cg::grid_group grid = cg::this_grid();

    const int blk = blockIdx.x;
    const int b = blk >> 3;
    const int j = blk & 7;
    const int t = threadIdx.x;
    const int wv = t >> 6, lane = t & 63;
    const float* xb = x + ((size_t)b * CH + (size_t)j * CPB) * NPix;

    // ---- phase 1: L2 norms of this block's 128 rows (one wave per row) ----
    for (int row = wv; row < CPB; row += 13) {
        const float4* r4 = (const float4*)(xb + (size_t)row * NPix); // 196 float4
        float s = 0.f;
        #pragma unroll
        for (int i = 0; i < 3; i++) {
            float4 v = r4[i * 64 + lane];
            s += v.x*v.x + v.y*v.y + v.z*v.z + v.w*v.w;
        }
        if (lane < 4) {
            float4 v = r4[192 + lane];
            s += v.x*v.x + v.y*v.y + v.z*v.z + v.w*v.w;
        }
        s = wave_reduce(s);
        if (lane == 0) inv_l[row] = 1.f / fmaxf(sqrtf(s), 1e-10f);
    }
    __syncthreads();

    // ---- w'[m][p] = Wm[m,p] * inv ----
    if (t < CPB) {
        float inv = inv_l[t];
        #pragma unroll
        for (int m = 0; m < MMOD; m++)
            wl[m][t] = Wm[m * CH + j * CPB + t] * inv;
    }
    __syncthreads();

    // ---- phase 2: z partial over 128 channels; thread t owns pixel t ----
    if (t < NPix) {
        float a0 = 0.f, a1 = 0.f, a2 = 0.f, a3 = 0.f;
        const float* xp = xb + t;
        #pragma unroll 8
        for (int pp = 0; pp < CPB; pp++) {
            float xv = xp[(size_t)pp * NPix];   // coalesced; L2-warm from phase 1
            a0 += wl[0][pp] * xv;
            a1 += wl[1][pp] * xv;
            a2 += wl[2][pp] * xv;
            a3 += wl[3][pp] * xv;
        }
        size_t base = ((size_t)blk * MMOD) * NPix + t;
        zpart[base]            = a0;
        zpart[base + NPix]     = a1;
        zpart[base + 2 * NPix] = a2;
        zpart[base + 3 * NPix] = a3;
    }
    __threadfence();
    grid.sync();

    // ---- phase 3: j==0 blocks compute h[b,n] = sum_m g/s2 ----
    if (j == 0) {
        const bool act = (t < NPix);
        float g[MMOD];
        #pragma unroll
        for (int m = 0; m < MMOD; m++) {
            float z = 0.f;
            if (act) {
                #pragma unroll
                for (int jj = 0; jj < JCH; jj++)
                    z += zpart[(((size_t)(b * JCH + jj)) * MMOD + m) * NPix + t];
            }
            g[m] = act ? 1.f / (1.f + expf(-z)) : 0.f;
        }
        #pragma unroll
        for (int m = 0; m < MMOD; m++) {
            float s = wave_reduce(g[m] * g[m]);
            if (lane == 0) red[wv][m] = s;
        }
        __syncthreads();
        if (t < MMOD) {
            float s = 0.f;
            #pragma unroll
            for (int w = 0; w < 13; w++) s += red[w][t];
            s2s[t] = fmaxf(s, 1e-30f);
        }
        __syncthreads();
        if (act) {
            float hv = 0.f;
            #pragma unroll
            for (int m = 0; m < MMOD; m++) hv += g[m] / s2s[m];
            h[(size_t)b * NPix + t] = hv;
        }
    }
    __threadfence();
    grid.sync();

    // ---- phase 4: out[b,p] = inv * dot(x row, h[b]) for this block's rows ----
    if (t < NPix) h_l[t] = h[(size_t)b * NPix + t];
    __syncthreads();
    const float4* h4 = (const float4*)h_l;
    for (int row = wv; row < CPB; row += 13) {
        const float4* x4 = (const float4*)(xb + (size_t)row * NPix);
        float s = 0.f;
        #pragma unroll
        for (int i = 0; i < 3; i++) {
            float4 xv = x4[i * 64 + lane];
            float4 hv = h4[i * 64 + lane];
            s += xv.x*hv.x + xv.y*hv.y + xv.z*hv.z + xv.w*hv.w;
        }
        if (lane < 4) {
            float4 xv = x4[192 + lane];
            float4 hv = h4[192 + lane];
            s += xv.x*hv.x + xv.y*hv.y + xv.z*hv.z + xv.w*hv.w;
        }
        s = wave_reduce(s);
        if (lane == 0) {
            float v = s * inv_l[row];
            // nan_to_num semantics: nan->0, +/-inf -> +/-FLT_MAX
            if (!(v == v)) v = 0.f;
            v = fminf(fmaxf(v, -3.402823466e+38f), 3.402823466e+38f);
            out[b * CH + j * CPB + row] = v;
        }
    }
}

extern "C" void kernel_launch(void* const* d_in, const int* in_sizes, int n_in,
                              void* d_out, int out_size, void* d_ws, size_t ws_size,
                              hipStream_t stream) {
    const float* x  = (const float*)d_in[0];   // [32,1024,28,28]
    const float* Wm = (const float*)d_in[1];   // [4,1,1024]
    float* out = (float*)d_out;                // [32,1024]
    float* wsf = (float*)d_ws;

    float* zpart = wsf;                                     // 256*4*784 = 802816 floats
    float* h     = zpart + (size_t)BATCH * JCH * MMOD * NPix; // 25088 floats

    void* args[] = { (void*)&x, (void*)&Wm, (void*)&zpart, (void*)&h, (void*)&out };
    hipLaunchCooperativeKernel((const void*)k_fused, dim3(BATCH * JCH), dim3(TB),
                               args, 0, stream);
}

// Round 6
// 182.513 us; speedup vs baseline: 2.0379x; 2.0379x over previous
//
#include <hip/hip_runtime.h>
#include <math.h>

// Problem dims (fixed by reference)
#define BATCH 32
#define CH    1024     // C == P
#define NPix  784      // H*W = 28*28
#define MMOD  4        // M models, Q == 1
#define NPC   32       // p-chunks
#define PPC   32       // channels per chunk (NPC*PPC == CH)
#define T2    832      // 13 waves: covers 784 pixels

__device__ __forceinline__ float wave_reduce(float s) {
    #pragma unroll
    for (int off = 32; off; off >>= 1) s += __shfl_down(s, off, 64);
    return s;
}

// Wave64 sum on the VALU pipe (DPP), no DS-pipe traffic.
// row_shr 1/2/4/8 then row_bcast15 (rows 1,3) + row_bcast31 (rows 2,3).
// Full sum lands in lane 63. bound_ctrl=true: invalid-source lanes read 0.
__device__ __forceinline__ float dpp_wave_sum(float v) {
    int x;
    x = __builtin_amdgcn_update_dpp(0, __builtin_bit_cast(int, v), 0x111, 0xf, 0xf, true);
    v += __builtin_bit_cast(float, x);
    x = __builtin_amdgcn_update_dpp(0, __builtin_bit_cast(int, v), 0x112, 0xf, 0xf, true);
    v += __builtin_bit_cast(float, x);
    x = __builtin_amdgcn_update_dpp(0, __builtin_bit_cast(int, v), 0x114, 0xf, 0xf, true);
    v += __builtin_bit_cast(float, x);
    x = __builtin_amdgcn_update_dpp(0, __builtin_bit_cast(int, v), 0x118, 0xf, 0xf, true);
    v += __builtin_bit_cast(float, x);
    x = __builtin_amdgcn_update_dpp(0, __builtin_bit_cast(int, v), 0x142, 0xa, 0xf, true);
    v += __builtin_bit_cast(float, x);
    x = __builtin_amdgcn_update_dpp(0, __builtin_bit_cast(int, v), 0x143, 0xc, 0xf, true);
    v += __builtin_bit_cast(float, x);
    return v;
}

// Single-pass norms + z-partials: x read from memory EXACTLY once.
// Block (b,pc) owns 32 channels; thread t holds pixel t of each in xv[32]
// (independent loads -> full MLP; R3's trap was dependent per-row chains).
// Phase A: per-channel squares, DPP wave-sum (VALU pipe), 1 ds_write/ch/wave.
// Phase A2: 32 threads finish norms, build w'[p][m] = Wm*inv in LDS (float4).
// Phase B: z_m += w'[p][m] * xv[p], one b128 LDS broadcast per channel.
__global__ __launch_bounds__(T2) void k_nz(const float* __restrict__ x,
                                           const float* __restrict__ Wm,
                                           float* __restrict__ inv_norm,
                                           float* __restrict__ zpart) {
    __shared__ float sq_l[PPC * 13];
    __shared__ float4 wl4[PPC];
    const int blk = blockIdx.x;
    const int b  = blk >> 5;        // / NPC
    const int pc = blk & (NPC - 1);
    const int t = threadIdx.x;
    const int wv = t >> 6, lane = t & 63;
    const bool act = (t < NPix);
    const float* xb = x + ((size_t)b * CH + (size_t)pc * PPC) * NPix;
    const float* xp = xb + (act ? t : 0);

    float xv[PPC];
    #pragma unroll
    for (int pp = 0; pp < PPC; pp++) xv[pp] = xp[(size_t)pp * NPix]; // coalesced
    if (!act) {
        #pragma unroll
        for (int pp = 0; pp < PPC; pp++) xv[pp] = 0.f;
    }

    #pragma unroll
    for (int pp = 0; pp < PPC; pp++) {
        float s = dpp_wave_sum(xv[pp] * xv[pp]);
        if (lane == 63) sq_l[pp * 13 + wv] = s;
    }
    __syncthreads();

    if (t < PPC) {
        float s = 0.f;
        #pragma unroll
        for (int w = 0; w < 13; w++) s += sq_l[t * 13 + w];
        const float inv = 1.f / fmaxf(sqrtf(s), 1e-10f);
        const int p = pc * PPC + t;
        inv_norm[b * CH + p] = inv;
        float4 w4;
        w4.x = Wm[0 * CH + p] * inv;
        w4.y = Wm[1 * CH + p] * inv;
        w4.z = Wm[2 * CH + p] * inv;
        w4.w = Wm[3 * CH + p] * inv;
        wl4[t] = w4;
    }
    __syncthreads();

    if (act) {
        float a0 = 0.f, a1 = 0.f, a2 = 0.f, a3 = 0.f;
        #pragma unroll
        for (int pp = 0; pp < PPC; pp++) {
            float4 w = wl4[pp];          // ds_read_b128, same-addr broadcast
            a0 += w.x * xv[pp];
            a1 += w.y * xv[pp];
            a2 += w.z * xv[pp];
            a3 += w.w * xv[pp];
        }
        size_t base = ((size_t)blk * MMOD) * NPix + t;
        zpart[base]            = a0;
        zpart[base + NPix]     = a1;
        zpart[base + 2 * NPix] = a2;
        zpart[base + 3 * NPix] = a3;
    }
}

// Reduce zpart over 32 chunks, sigmoid, s2 = sum g^2 per m, h = sum_m g/s2.
__global__ __launch_bounds__(T2) void k_gh(const float* __restrict__ zpart,
                                           float* __restrict__ h) {
    __shared__ float red[13][MMOD];
    __shared__ float s2s[MMOD];
    const int b = blockIdx.x;
    const int t = threadIdx.x;
    const int wv = t >> 6, lane = t & 63;
    const bool act = (t < NPix);

    float g[MMOD];
    #pragma unroll
    for (int m = 0; m < MMOD; m++) {
        float z = 0.f;
        if (act) {
            #pragma unroll 8
            for (int pc = 0; pc < NPC; pc++)
                z += zpart[(((size_t)b * NPC + pc) * MMOD + m) * NPix + t];
        }
        g[m] = act ? 1.f / (1.f + expf(-z)) : 0.f;
    }
    #pragma unroll
    for (int m = 0; m < MMOD; m++) {
        float s = wave_reduce(g[m] * g[m]);
        if (lane == 0) red[wv][m] = s;
    }
    __syncthreads();
    if (t < MMOD) {
        float s = 0.f;
        #pragma unroll
        for (int w = 0; w < 13; w++) s += red[w][t];
        s2s[t] = fmaxf(s, 1e-30f);
    }
    __syncthreads();
    if (act) {
        float hv = 0.f;
        #pragma unroll
        for (int m = 0; m < MMOD; m++) hv += g[m] / s2s[m];
        h[(size_t)b * NPix + t] = hv;
    }
}

// out[b,p] = inv_norm[b,p] * dot(x[b,p,:], h[b,:]). One wave per row.
__global__ __launch_bounds__(256) void k_out(const float* __restrict__ x,
                                             const float* __restrict__ h,
                                             const float* __restrict__ inv_norm,
                                             float* __restrict__ out) {
    const int r = blockIdx.x * 4 + (threadIdx.x >> 6);  // r in [0, 32768)
    const int lane = threadIdx.x & 63;
    const int b = r >> 10;
    const float4* x4 = (const float4*)(x + (size_t)r * NPix);
    const float4* h4 = (const float4*)(h + (size_t)b * NPix);
    float s = 0.f;
    #pragma unroll
    for (int i = 0; i < 3; i++) {
        float4 xv = x4[i * 64 + lane];
        float4 hv = h4[i * 64 + lane];
        s += xv.x*hv.x + xv.y*hv.y + xv.z*hv.z + xv.w*hv.w;
    }
    if (lane < 4) {
        float4 xv = x4[192 + lane];
        float4 hv = h4[192 + lane];
        s += xv.x*hv.x + xv.y*hv.y + xv.z*hv.z + xv.w*hv.w;
    }
    s = wave_reduce(s);
    if (lane == 0) {
        float v = s * inv_norm[r];
        // nan_to_num semantics: nan->0, +/-inf -> +/-FLT_MAX
        if (!(v == v)) v = 0.f;
        v = fminf(fmaxf(v, -3.402823466e+38f), 3.402823466e+38f);
        out[r] = v;
    }
}

extern "C" void kernel_launch(void* const* d_in, const int* in_sizes, int n_in,
                              void* d_out, int out_size, void* d_ws, size_t ws_size,
                              hipStream_t stream) {
    const float* x  = (const float*)d_in[0];   // [32,1024,28,28]
    const float* Wm = (const float*)d_in[1];   // [4,1,1024]
    float* out = (float*)d_out;                // [32,1024]
    float* wsf = (float*)d_ws;

    float* inv_norm = wsf;                                        // 32768 floats
    float* zpart    = inv_norm + BATCH * CH;                      // 32*32*4*784 floats
    float* h        = zpart + (size_t)BATCH * NPC * MMOD * NPix;  // 25088 floats

    k_nz<<<BATCH * NPC, T2, 0, stream>>>(x, Wm, inv_norm, zpart);
    k_gh<<<BATCH, T2, 0, stream>>>(zpart, h);
    k_out<<<BATCH * CH / 4, 256, 0, stream>>>(x, h, inv_norm, out);
}

// Round 7
// 176.094 us; speedup vs baseline: 2.1122x; 1.0365x over previous
//
#include <hip/hip_runtime.h>
#include <math.h>

// Problem dims (fixed by reference)
#define BATCH 32
#define CH    1024     // C == P
#define NPix  784      // H*W = 28*28
#define MMOD  4        // M models, Q == 1
#define NPC   64       // p-chunks (k_nz)
#define PPC   16       // channels per chunk (NPC*PPC == CH)
#define K1B   256      // k_nz block: 4 waves
#define NF4   196      // float4 per 784-pixel row
#define T2    832      // 13 waves: covers 784 pixels

__device__ __forceinline__ float wave_reduce(float s) {
    #pragma unroll
    for (int off = 32; off; off >>= 1) s += __shfl_down(s, off, 64);
    return s;
}

// Wave64 sum on the VALU pipe (DPP; verified correct in R6).
// Full sum lands in lane 63.
__device__ __forceinline__ float dpp_wave_sum(float v) {
    int x;
    x = __builtin_amdgcn_update_dpp(0, __builtin_bit_cast(int, v), 0x111, 0xf, 0xf, true);
    v += __builtin_bit_cast(float, x);
    x = __builtin_amdgcn_update_dpp(0, __builtin_bit_cast(int, v), 0x112, 0xf, 0xf, true);
    v += __builtin_bit_cast(float, x);
    x = __builtin_amdgcn_update_dpp(0, __builtin_bit_cast(int, v), 0x114, 0xf, 0xf, true);
    v += __builtin_bit_cast(float, x);
    x = __builtin_amdgcn_update_dpp(0, __builtin_bit_cast(int, v), 0x118, 0xf, 0xf, true);
    v += __builtin_bit_cast(float, x);
    x = __builtin_amdgcn_update_dpp(0, __builtin_bit_cast(int, v), 0x142, 0xa, 0xf, true);
    v += __builtin_bit_cast(float, x);
    x = __builtin_amdgcn_update_dpp(0, __builtin_bit_cast(int, v), 0x143, 0xc, 0xf, true);
    v += __builtin_bit_cast(float, x);
    return v;
}

// Single-pass norms + z-partials, 16 B/lane edition (R6 post-mortem: 32
// scalar dword loads/thread ran at 2.3 TB/s — VMEM-issue-limited, not BW).
// Block (b,pc) owns 16 channels; thread t<196 holds float4 (pixels 4t..4t+3)
// of each channel: 16 independent dwordx4 loads. Norms: DPP wave-sum +
// LDS cross-wave combine. Phase B: float4 z accumulators, float4 stores.
__global__ __launch_bounds__(K1B) void k_nz(const float* __restrict__ x,
                                            const float* __restrict__ Wm,
                                            float* __restrict__ inv_norm,
                                            float* __restrict__ zpart) {
    __shared__ float sq_l[PPC][4];
    __shared__ float4 wl4[PPC];
    const int blk = blockIdx.x;
    const int b  = blk >> 6;         // / NPC
    const int pc = blk & (NPC - 1);
    const int t = threadIdx.x;
    const int wv = t >> 6, lane = t & 63;
    const bool act = (t < NF4);
    const float4* xb4 = (const float4*)(x + ((size_t)b * CH + (size_t)pc * PPC) * NPix);
    const int tt = act ? t : 0;

    float4 xv[PPC];
    #pragma unroll
    for (int pp = 0; pp < PPC; pp++) xv[pp] = xb4[pp * NF4 + tt];  // 16B/lane, coalesced

    #pragma unroll
    for (int pp = 0; pp < PPC; pp++) {
        float4 v = xv[pp];
        float s = act ? (v.x*v.x + v.y*v.y + v.z*v.z + v.w*v.w) : 0.f;
        s = dpp_wave_sum(s);
        if (lane == 63) sq_l[pp][wv] = s;
    }
    __syncthreads();

    if (t < PPC) {
        const float s = sq_l[t][0] + sq_l[t][1] + sq_l[t][2] + sq_l[t][3];
        const float inv = 1.f / fmaxf(sqrtf(s), 1e-10f);
        const int p = pc * PPC + t;
        inv_norm[b * CH + p] = inv;
        float4 w4;
        w4.x = Wm[0 * CH + p] * inv;
        w4.y = Wm[1 * CH + p] * inv;
        w4.z = Wm[2 * CH + p] * inv;
        w4.w = Wm[3 * CH + p] * inv;
        wl4[t] = w4;
    }
    __syncthreads();

    if (act) {
        float4 a0 = {0,0,0,0}, a1 = {0,0,0,0}, a2 = {0,0,0,0}, a3 = {0,0,0,0};
        #pragma unroll
        for (int pp = 0; pp < PPC; pp++) {
            const float4 w = wl4[pp];     // ds_read_b128, same-addr broadcast
            const float4 v = xv[pp];
            a0.x += w.x*v.x; a0.y += w.x*v.y; a0.z += w.x*v.z; a0.w += w.x*v.w;
            a1.x += w.y*v.x; a1.y += w.y*v.y; a1.z += w.y*v.z; a1.w += w.y*v.w;
            a2.x += w.z*v.x; a2.y += w.z*v.y; a2.z += w.z*v.z; a2.w += w.z*v.w;
            a3.x += w.w*v.x; a3.y += w.w*v.y; a3.z += w.w*v.z; a3.w += w.w*v.w;
        }
        float4* zp = (float4*)(zpart + ((size_t)blk * MMOD) * NPix);
        zp[0 * NF4 + t] = a0;
        zp[1 * NF4 + t] = a1;
        zp[2 * NF4 + t] = a2;
        zp[3 * NF4 + t] = a3;
    }
}

// Per (b,m) block (grid 128 — R6's 32-block k_gh used only 32 CUs):
// z = sum over 64 chunks, g = sigmoid(z), s2 = block-reduced sum g^2.
__global__ __launch_bounds__(T2) void k_gh(const float* __restrict__ zpart,
                                           float* __restrict__ g_out,
                                           float* __restrict__ s2g) {
    __shared__ float red[13];
    const int blk = blockIdx.x;
    const int b = blk >> 2;
    const int m = blk & 3;
    const int t = threadIdx.x;
    const int wv = t >> 6, lane = t & 63;
    const bool act = (t < NPix);

    float z = 0.f;
    if (act) {
        #pragma unroll 8
        for (int pc = 0; pc < NPC; pc++)
            z += zpart[(((size_t)(b * NPC + pc)) * MMOD + m) * NPix + t];
    }
    const float g = act ? 1.f / (1.f + expf(-z)) : 0.f;
    float s = wave_reduce(g * g);
    if (lane == 0) red[wv] = s;
    __syncthreads();
    if (t == 0) {
        float ss = 0.f;
        #pragma unroll
        for (int w = 0; w < 13; w++) ss += red[w];
        s2g[blk] = fmaxf(ss, 1e-30f);
    }
    if (act) g_out[(size_t)blk * NPix + t] = g;
}

// h[b,n] = sum_m g[b,m,n] / s2[b,m]. Tiny (32 blocks, ~1us).
__global__ __launch_bounds__(T2) void k_h(const float* __restrict__ g_out,
                                          const float* __restrict__ s2g,
                                          float* __restrict__ h) {
    const int b = blockIdx.x;
    const int t = threadIdx.x;
    if (t < NPix) {
        float hv = 0.f;
        #pragma unroll
        for (int m = 0; m < MMOD; m++)
            hv += g_out[(size_t)(b * MMOD + m) * NPix + t] / s2g[b * MMOD + m];
        h[(size_t)b * NPix + t] = hv;
    }
}

// out[b,p] = inv_norm[b,p] * dot(x[b,p,:], h[b,:]). One wave per row,
// float4 throughout (already ~L3-stream-bound in R4/R6).
__global__ __launch_bounds__(256) void k_out(const float* __restrict__ x,
                                             const float* __restrict__ h,
                                             const float* __restrict__ inv_norm,
                                             float* __restrict__ out) {
    const int r = blockIdx.x * 4 + (threadIdx.x >> 6);  // r in [0, 32768)
    const int lane = threadIdx.x & 63;
    const int b = r >> 10;
    const float4* x4 = (const float4*)(x + (size_t)r * NPix);
    const float4* h4 = (const float4*)(h + (size_t)b * NPix);
    float s = 0.f;
    #pragma unroll
    for (int i = 0; i < 3; i++) {
        float4 xv = x4[i * 64 + lane];
        float4 hv = h4[i * 64 + lane];
        s += xv.x*hv.x + xv.y*hv.y + xv.z*hv.z + xv.w*hv.w;
    }
    if (lane < 4) {
        float4 xv = x4[192 + lane];
        float4 hv = h4[192 + lane];
        s += xv.x*hv.x + xv.y*hv.y + xv.z*hv.z + xv.w*hv.w;
    }
    s = wave_reduce(s);
    if (lane == 0) {
        float v = s * inv_norm[r];
        // nan_to_num semantics: nan->0, +/-inf -> +/-FLT_MAX
        if (!(v == v)) v = 0.f;
        v = fminf(fmaxf(v, -3.402823466e+38f), 3.402823466e+38f);
        out[r] = v;
    }
}

extern "C" void kernel_launch(void* const* d_in, const int* in_sizes, int n_in,
                              void* d_out, int out_size, void* d_ws, size_t ws_size,
                              hipStream_t stream) {
    const float* x  = (const float*)d_in[0];   // [32,1024,28,28]
    const float* Wm = (const float*)d_in[1];   // [4,1,1024]
    float* out = (float*)d_out;                // [32,1024]
    float* wsf = (float*)d_ws;

    float* inv_norm = wsf;                                        // 32768 floats
    float* zpart    = inv_norm + BATCH * CH;                      // 32*64*4*784 = 6422528 floats
    float* g_out    = zpart + (size_t)BATCH * NPC * MMOD * NPix;  // 32*4*784 = 100352 floats
    float* s2g      = g_out + (size_t)BATCH * MMOD * NPix;        // 128 floats
    float* h        = s2g + BATCH * MMOD;                         // 25088 floats

    k_nz<<<BATCH * NPC, K1B, 0, stream>>>(x, Wm, inv_norm, zpart);
    k_gh<<<BATCH * MMOD, T2, 0, stream>>>(zpart, g_out, s2g);
    k_h<<<BATCH, T2, 0, stream>>>(g_out, s2g, h);
    k_out<<<BATCH * CH / 4, 256, 0, stream>>>(x, h, inv_norm, out);
}